// Round 1
// baseline (20665.965 us; speedup 1.0000x reference)
//
#include <hip/hip_runtime.h>
#include <math.h>

#define B_ 128
#define T_ 100
#define F_ 64
#define ROWLEN 68   // padded row: [0]=zero (f=-1), [1..64]=data, [65..67]=zero; 16B-aligned

// ---------------------------------------------------------------------------
// Inner conv helpers
// ---------------------------------------------------------------------------

template<int ROWS, int FT>
__device__ __forceinline__ void accum_row(const float* __restrict__ row,   // points at padded row + f0
                                          const float* __restrict__ wk,    // wl + (ci*3)*ROWS + ch*4
                                          float acc[4][FT])
{
    float v[FT + 2];
    if (FT == 4) {
        float4 a = *reinterpret_cast<const float4*>(row);
        float2 b = *reinterpret_cast<const float2*>(row + 4);
        v[0] = a.x; v[1] = a.y; v[2] = a.z; v[3] = a.w; v[4] = b.x; v[5] = b.y;
    } else {
        float2 a = *reinterpret_cast<const float2*>(row);
        float2 b = *reinterpret_cast<const float2*>(row + 2);
        v[0] = a.x; v[1] = a.y; v[2] = b.x; v[3] = b.y;
    }
#pragma unroll
    for (int d = 0; d < 3; ++d) {
        float4 w4 = *reinterpret_cast<const float4*>(wk + d * ROWS);
#pragma unroll
        for (int j = 0; j < FT; ++j) {
            acc[0][j] = fmaf(w4.x, v[j + d], acc[0][j]);
            acc[1][j] = fmaf(w4.y, v[j + d], acc[1][j]);
            acc[2][j] = fmaf(w4.z, v[j + d], acc[2][j]);
            acc[3][j] = fmaf(w4.w, v[j + d], acc[3][j]);
        }
    }
}

// Computes pre-activation gate accumulators for one thread's (ch, f0..f0+FT-1) tile.
// Input channels: CINX rows in xrows, CH rows in hrows (the layer's own hidden).
template<int CH, int CINX, int FT>
__device__ __forceinline__ void conv_gates(const float* __restrict__ xrows,
                                           const float* __restrict__ hrows,
                                           const float* __restrict__ wl,   // [ (CINX+CH)*3 ][ 4*CH ]
                                           int ch, int f0, float acc[4][FT])
{
    constexpr int ROWS = 4 * CH;
#pragma unroll
    for (int g = 0; g < 4; ++g)
#pragma unroll
        for (int j = 0; j < FT; ++j) acc[g][j] = 0.f;

    const float* wp = wl + ch * 4;
    for (int ci = 0; ci < CINX; ++ci)
        accum_row<ROWS, FT>(xrows + ci * ROWLEN + f0, wp + (ci * 3) * ROWS, acc);
    for (int ci = 0; ci < CH; ++ci)
        accum_row<ROWS, FT>(hrows + ci * ROWLEN + f0, wp + ((CINX + ci) * 3) * ROWS, acc);
}

__device__ __forceinline__ float sigm_(float x) { return 1.f / (1.f + expf(-x)); }

template<int CH, int FT>
__device__ __forceinline__ void gate_update(const float acc[4][FT],
                                            const float* __restrict__ bs,   // [4*CH] raw gate order
                                            const float* __restrict__ cbuf, // [CH][64]
                                            int ch, int f0, float hn[FT], float cn[FT])
{
    const float bi = bs[ch];
    const float bf = bs[CH + ch];
    const float bo = bs[2 * CH + ch];
    const float bg = bs[3 * CH + ch];
#pragma unroll
    for (int j = 0; j < FT; ++j) {
        float zi = acc[0][j] + bi;
        float zf = acc[1][j] + bf;
        float zo = acc[2][j] + bo;
        float zg = acc[3][j] + bg;
        float cold = cbuf[ch * 64 + f0 + j];
        float cc = sigm_(zf) * cold + sigm_(zi) * tanhf(zg);
        cn[j] = cc;
        hn[j] = sigm_(zo) * tanhf(cc);
    }
}

// ---------------------------------------------------------------------------
// Kernel 1: fused encoder (layer0: 1+16 -> 16, layer1: 16+32 -> 32)
// Writes enc2 hidden sequence to seq[T][B][32][64] and final states.
// ---------------------------------------------------------------------------
__global__ __launch_bounds__(512, 1) void enc_kernel(
    const float* __restrict__ x,
    const float* __restrict__ w0, const float* __restrict__ b0,
    const float* __restrict__ w1, const float* __restrict__ b1,
    float* __restrict__ seq,
    float* __restrict__ h1f, float* __restrict__ c1f,
    float* __restrict__ h2f, float* __restrict__ c2f)
{
    __shared__ float wl0[51 * 64];     // k=ci*3+d (ci<17), r=ch*4+g (CH=16)
    __shared__ float wl1[144 * 128];   // ci<48, CH=32
    __shared__ float bs0[64];
    __shared__ float bs1[128];
    __shared__ float xp[ROWLEN];
    __shared__ float h0p[16 * ROWLEN];
    __shared__ float c0[16 * 64];
    __shared__ float h1p[32 * ROWLEN];
    __shared__ float c1[32 * 64];

    const int tid = threadIdx.x;
    const int b = blockIdx.x;

    // stage weights, permuted: wl[k][ch*4+g] = w[(g*CH+ch), ci, d, 1]
    for (int idx = tid; idx < 51 * 64; idx += 512) {
        int k = idx >> 6, r = idx & 63;
        int ch = r >> 2, g = r & 3;
        int ci = k / 3, d = k - ci * 3;
        wl0[idx] = w0[((g * 16 + ch) * 17 + ci) * 9 + d * 3 + 1];
    }
    for (int idx = tid; idx < 144 * 128; idx += 512) {
        int k = idx >> 7, r = idx & 127;
        int ch = r >> 2, g = r & 3;
        int ci = k / 3, d = k - ci * 3;
        wl1[idx] = w1[((g * 32 + ch) * 48 + ci) * 9 + d * 3 + 1];
    }
    if (tid < 64) bs0[tid] = b0[tid];
    if (tid < 128) bs1[tid] = b1[tid];
    for (int i = tid; i < ROWLEN; i += 512) xp[i] = 0.f;
    for (int i = tid; i < 16 * ROWLEN; i += 512) h0p[i] = 0.f;
    for (int i = tid; i < 16 * 64; i += 512) c0[i] = 0.f;
    for (int i = tid; i < 32 * ROWLEN; i += 512) h1p[i] = 0.f;
    for (int i = tid; i < 32 * 64; i += 512) c1[i] = 0.f;
    __syncthreads();

    const int ch0 = tid >> 5, f00 = (tid & 31) * 2;   // layer0: 16ch x 32fg, FT=2
    const int ch1 = tid >> 4, f01 = (tid & 15) * 4;   // layer1: 32ch x 16fg, FT=4

    for (int t = 0; t < T_; ++t) {
        if (tid < 64) xp[1 + tid] = x[(b * T_ + t) * 64 + tid];
        __syncthreads();

        // ---- layer 0 ----
        float acc0[4][2], hn0[2], cn0[2];
        conv_gates<16, 1, 2>(xp, h0p, wl0, ch0, f00, acc0);
        gate_update<16, 2>(acc0, bs0, c0, ch0, f00, hn0, cn0);
        __syncthreads();
#pragma unroll
        for (int j = 0; j < 2; ++j) {
            h0p[ch0 * ROWLEN + 1 + f00 + j] = hn0[j];
            c0[ch0 * 64 + f00 + j] = cn0[j];
        }
        __syncthreads();

        // ---- layer 1 (input = new h0) ----
        float acc1[4][4], hn1[4], cn1[4];
        conv_gates<32, 16, 4>(h0p, h1p, wl1, ch1, f01, acc1);
        gate_update<32, 4>(acc1, bs1, c1, ch1, f01, hn1, cn1);
        __syncthreads();
#pragma unroll
        for (int j = 0; j < 4; ++j) {
            h1p[ch1 * ROWLEN + 1 + f01 + j] = hn1[j];
            c1[ch1 * 64 + f01 + j] = cn1[j];
        }
        // write enc2 hidden to global sequence
        float4 hv = make_float4(hn1[0], hn1[1], hn1[2], hn1[3]);
        *reinterpret_cast<float4*>(&seq[(((size_t)t * B_ + b) * 32 + ch1) * 64 + f01]) = hv;
        __syncthreads();
    }

    // final states: layer0 -> (h1f,c1f), layer1 -> (h2f,c2f)
    for (int i = tid; i < 16 * 64; i += 512) {
        int ch = i >> 6, f = i & 63;
        h1f[(b * 16 + ch) * 64 + f] = h0p[ch * ROWLEN + 1 + f];
        c1f[(b * 16 + ch) * 64 + f] = c0[i];
    }
    for (int i = tid; i < 32 * 64; i += 512) {
        int ch = i >> 6, f = i & 63;
        h2f[(b * 32 + ch) * 64 + f] = h1p[ch * ROWLEN + 1 + f];
        c2f[(b * 32 + ch) * 64 + f] = c1[i];
    }
}

// ---------------------------------------------------------------------------
// Kernel 2: decoder layer 0 (32+32 -> 32), init from (h2f,c2f).
// Reads seq[t][b] (enc2 hidden), overwrites it in place with its own hidden.
// ---------------------------------------------------------------------------
__global__ __launch_bounds__(512, 1) void dec0_kernel(
    const float* __restrict__ w, const float* __restrict__ bias,
    float* __restrict__ seq,
    const float* __restrict__ h2f, const float* __restrict__ c2f)
{
    __shared__ float wl[192 * 128];    // ci<64, CH=32
    __shared__ float bs[128];
    __shared__ float xin[32 * ROWLEN];
    __shared__ float hp[32 * ROWLEN];
    __shared__ float c[32 * 64];

    const int tid = threadIdx.x;
    const int b = blockIdx.x;

    for (int idx = tid; idx < 192 * 128; idx += 512) {
        int k = idx >> 7, r = idx & 127;
        int ch = r >> 2, g = r & 3;
        int ci = k / 3, d = k - ci * 3;
        wl[idx] = w[((g * 32 + ch) * 64 + ci) * 9 + d * 3 + 1];
    }
    if (tid < 128) bs[tid] = bias[tid];
    for (int i = tid; i < 32 * ROWLEN; i += 512) { xin[i] = 0.f; hp[i] = 0.f; }
    __syncthreads();
    for (int i = tid; i < 32 * 64; i += 512) {
        int ch = i >> 6, f = i & 63;
        hp[ch * ROWLEN + 1 + f] = h2f[(b * 32 + ch) * 64 + f];
        c[i] = c2f[(b * 32 + ch) * 64 + f];
    }
    __syncthreads();

    const int ch = tid >> 4, f0 = (tid & 15) * 4;

    for (int t = 0; t < T_; ++t) {
        {   // stage input tile (coalesced float4 per thread)
            float4 vv = *reinterpret_cast<const float4*>(&seq[((size_t)t * B_ + b) * 2048 + tid * 4]);
            int ci = (tid * 4) >> 6, f = (tid * 4) & 63;
            float* dst = &xin[ci * ROWLEN + 1 + f];
            dst[0] = vv.x; dst[1] = vv.y; dst[2] = vv.z; dst[3] = vv.w;
        }
        __syncthreads();

        float acc[4][4], hn[4], cn[4];
        conv_gates<32, 32, 4>(xin, hp, wl, ch, f0, acc);
        gate_update<32, 4>(acc, bs, c, ch, f0, hn, cn);
        __syncthreads();
#pragma unroll
        for (int j = 0; j < 4; ++j) {
            hp[ch * ROWLEN + 1 + f0 + j] = hn[j];
            c[ch * 64 + f0 + j] = cn[j];
        }
        float4 hv = make_float4(hn[0], hn[1], hn[2], hn[3]);
        *reinterpret_cast<float4*>(&seq[((size_t)t * B_ + b) * 2048 + ch * 64 + f0]) = hv;   // in place
    }
}

// ---------------------------------------------------------------------------
// Kernel 3: decoder layer 1 (32+16 -> 16) + final 1x1 conv, init from (h1f,c1f).
// Reads seq (dec0 hidden), writes recon directly to d_out [B][T][F].
// ---------------------------------------------------------------------------
__global__ __launch_bounds__(512, 1) void dec1_kernel(
    const float* __restrict__ w, const float* __restrict__ bias,
    const float* __restrict__ seq,
    const float* __restrict__ h1f, const float* __restrict__ c1f,
    const float* __restrict__ fw, const float* __restrict__ fb,
    float* __restrict__ out)
{
    __shared__ float wl[144 * 64];     // ci<48, CH=16
    __shared__ float bs[64];
    __shared__ float xin[32 * ROWLEN];
    __shared__ float hp[16 * ROWLEN];
    __shared__ float c[16 * 64];
    __shared__ float fcw[16];
    __shared__ float fcb;

    const int tid = threadIdx.x;
    const int b = blockIdx.x;

    for (int idx = tid; idx < 144 * 64; idx += 512) {
        int k = idx >> 6, r = idx & 63;
        int ch = r >> 2, g = r & 3;
        int ci = k / 3, d = k - ci * 3;
        wl[idx] = w[((g * 16 + ch) * 48 + ci) * 9 + d * 3 + 1];
    }
    if (tid < 64) bs[tid] = bias[tid];
    if (tid < 16) fcw[tid] = fw[tid];
    if (tid == 16) fcb = fb[0];
    for (int i = tid; i < 32 * ROWLEN; i += 512) xin[i] = 0.f;
    for (int i = tid; i < 16 * ROWLEN; i += 512) hp[i] = 0.f;
    __syncthreads();
    for (int i = tid; i < 16 * 64; i += 512) {
        int ch = i >> 6, f = i & 63;
        hp[ch * ROWLEN + 1 + f] = h1f[(b * 16 + ch) * 64 + f];
        c[i] = c1f[(b * 16 + ch) * 64 + f];
    }
    __syncthreads();

    const int ch = tid >> 5, f0 = (tid & 31) * 2;

    for (int t = 0; t < T_; ++t) {
        {
            float4 vv = *reinterpret_cast<const float4*>(&seq[((size_t)t * B_ + b) * 2048 + tid * 4]);
            int ci = (tid * 4) >> 6, f = (tid * 4) & 63;
            float* dst = &xin[ci * ROWLEN + 1 + f];
            dst[0] = vv.x; dst[1] = vv.y; dst[2] = vv.z; dst[3] = vv.w;
        }
        __syncthreads();

        float acc[4][2], hn[2], cn[2];
        conv_gates<16, 32, 2>(xin, hp, wl, ch, f0, acc);
        gate_update<16, 2>(acc, bs, c, ch, f0, hn, cn);
        __syncthreads();
#pragma unroll
        for (int j = 0; j < 2; ++j) {
            hp[ch * ROWLEN + 1 + f0 + j] = hn[j];
            c[ch * 64 + f0 + j] = cn[j];
        }
        __syncthreads();

        // final 1x1 conv over the 16 hidden channels -> out[b][t][f]
        if (tid < 64) {
            float a = fcb;
#pragma unroll
            for (int k2 = 0; k2 < 16; ++k2)
                a = fmaf(fcw[k2], hp[k2 * ROWLEN + 1 + tid], a);
            out[(b * T_ + t) * 64 + tid] = a;
        }
        __syncthreads();
    }
}

// ---------------------------------------------------------------------------
extern "C" void kernel_launch(void* const* d_in, const int* in_sizes, int n_in,
                              void* d_out, int out_size, void* d_ws, size_t ws_size,
                              hipStream_t stream)
{
    (void)in_sizes; (void)n_in; (void)out_size; (void)ws_size;
    const float* x   = (const float*)d_in[0];
    const float* ew0 = (const float*)d_in[1];
    const float* eb0 = (const float*)d_in[2];
    const float* ew1 = (const float*)d_in[3];
    const float* eb1 = (const float*)d_in[4];
    const float* dw0 = (const float*)d_in[5];
    const float* db0 = (const float*)d_in[6];
    const float* dw1 = (const float*)d_in[7];
    const float* db1 = (const float*)d_in[8];
    const float* fw  = (const float*)d_in[9];
    const float* fb  = (const float*)d_in[10];
    float* out = (float*)d_out;

    float* ws  = (float*)d_ws;
    float* seq = ws;                                     // [T][B][32][64]
    float* h1f = seq + (size_t)T_ * B_ * 32 * 64;        // [B][16][64]
    float* c1f = h1f + (size_t)B_ * 16 * 64;
    float* h2f = c1f + (size_t)B_ * 16 * 64;             // [B][32][64]
    float* c2f = h2f + (size_t)B_ * 32 * 64;

    enc_kernel<<<B_, 512, 0, stream>>>(x, ew0, eb0, ew1, eb1, seq, h1f, c1f, h2f, c2f);
    dec0_kernel<<<B_, 512, 0, stream>>>(dw0, db0, seq, h2f, c2f);
    dec1_kernel<<<B_, 512, 0, stream>>>(dw1, db1, seq, h1f, c1f, fw, fb, out);
}

// Round 2
// 3007.042 us; speedup vs baseline: 6.8725x; 6.8725x over previous
//
#include <hip/hip_runtime.h>
#include <math.h>

#define B_ 128
#define T_ 100
#define ROWLEN 68   // padded row: [0]=f=-1 (zero), [1..64]=data, [65..67]=zero

// ---------------------------------------------------------------------------
// Fast transcendentals: v_exp_f32 + v_rcp_f32 (~1e-6 rel err, threshold 1.27e-4)
// ---------------------------------------------------------------------------
__device__ __forceinline__ float frcp_(float x) { return __builtin_amdgcn_rcpf(x); }
__device__ __forceinline__ float fsig_(float x) { return frcp_(1.f + __expf(-x)); }
__device__ __forceinline__ float ftanh_(float x) {
    float e = __expf(2.f * x);           // tanh = 1 - 2/(e^{2x}+1); exact limits at +/-inf
    return 1.f - 2.f * frcp_(e + 1.f);
}

// ---------------------------------------------------------------------------
// Scalar-only row accumulators (NO arrays -> nothing can spill to scratch).
// row points at padded row + f0 (row[0] is column f0-1). wk points at
// wl + (r*3)*ROWS + ch*4 ; weight for tap d is float4 at wk + d*ROWS.
// ---------------------------------------------------------------------------
template<int ROWS>
__device__ __forceinline__ void rowacc1(const float* __restrict__ row,
                                        const float* __restrict__ wk,
                                        float& a0, float& a1, float& a2, float& a3)
{
    float v0 = row[0], v1 = row[1], v2 = row[2];
#pragma unroll
    for (int d = 0; d < 3; ++d) {
        float4 w = *reinterpret_cast<const float4*>(wk + d * ROWS);
        float u = (d == 0) ? v0 : ((d == 1) ? v1 : v2);
        a0 = fmaf(w.x, u, a0);
        a1 = fmaf(w.y, u, a1);
        a2 = fmaf(w.z, u, a2);
        a3 = fmaf(w.w, u, a3);
    }
}

template<int ROWS>
__device__ __forceinline__ void rowacc2(const float* __restrict__ row,
                                        const float* __restrict__ wk,
                                        float& a00, float& a01, float& a10, float& a11,
                                        float& a20, float& a21, float& a30, float& a31)
{
    float2 p = *reinterpret_cast<const float2*>(row);
    float2 q = *reinterpret_cast<const float2*>(row + 2);
    float v0 = p.x, v1 = p.y, v2 = q.x, v3 = q.y;
#pragma unroll
    for (int d = 0; d < 3; ++d) {
        float4 w = *reinterpret_cast<const float4*>(wk + d * ROWS);
        float u0 = (d == 0) ? v0 : ((d == 1) ? v1 : v2);
        float u1 = (d == 0) ? v1 : ((d == 1) ? v2 : v3);
        a00 = fmaf(w.x, u0, a00); a01 = fmaf(w.x, u1, a01);
        a10 = fmaf(w.y, u0, a10); a11 = fmaf(w.y, u1, a11);
        a20 = fmaf(w.z, u0, a20); a21 = fmaf(w.z, u1, a21);
        a30 = fmaf(w.w, u0, a30); a31 = fmaf(w.w, u1, a31);
    }
}

// ---------------------------------------------------------------------------
// Kernel 1: fused encoder (layer0: 1+16 -> 16, layer1: 16+32 -> 32)
// ---------------------------------------------------------------------------
__global__ __launch_bounds__(1024, 4) void enc_kernel(
    const float* __restrict__ x,
    const float* __restrict__ w0, const float* __restrict__ b0,
    const float* __restrict__ w1, const float* __restrict__ b1,
    float* __restrict__ seq,
    float* __restrict__ h1f, float* __restrict__ c1f,
    float* __restrict__ h2f, float* __restrict__ c2f)
{
    __shared__ float wl0[51 * 64];     // k=r*3+d (r<17), col=ch*4+g (CH=16)
    __shared__ float wl1[144 * 128];   // r<48, CH=32
    __shared__ float bs0[64];
    __shared__ float bs1[128];
    __shared__ float xp[ROWLEN];
    __shared__ float h0p[16 * ROWLEN];
    __shared__ float c0[16 * 64];
    __shared__ float h1p[32 * ROWLEN];
    __shared__ float c1[32 * 64];

    const int tid = threadIdx.x;
    const int b = blockIdx.x;

    for (int idx = tid; idx < 51 * 64; idx += 1024) {
        int k = idx >> 6, r = idx & 63;
        int ch = r >> 2, g = r & 3;
        int ci = k / 3, d = k - ci * 3;
        wl0[idx] = w0[((g * 16 + ch) * 17 + ci) * 9 + d * 3 + 1];
    }
    for (int idx = tid; idx < 144 * 128; idx += 1024) {
        int k = idx >> 7, r = idx & 127;
        int ch = r >> 2, g = r & 3;
        int ci = k / 3, d = k - ci * 3;
        wl1[idx] = w1[((g * 32 + ch) * 48 + ci) * 9 + d * 3 + 1];
    }
    if (tid < 64) bs0[tid] = b0[tid];
    if (tid < 128) bs1[tid] = b1[tid];
    for (int i = tid; i < ROWLEN; i += 1024) xp[i] = 0.f;
    for (int i = tid; i < 16 * ROWLEN; i += 1024) h0p[i] = 0.f;
    for (int i = tid; i < 16 * 64; i += 1024) c0[i] = 0.f;
    for (int i = tid; i < 32 * ROWLEN; i += 1024) h1p[i] = 0.f;
    for (int i = tid; i < 32 * 64; i += 1024) c1[i] = 0.f;
    __syncthreads();

    const int chA = tid >> 6, fA = tid & 63;          // layer0: 16ch x 64f, FT=1
    const int chB = tid >> 5, fB = (tid & 31) * 2;    // layer1: 32ch x 32fg, FT=2

    for (int t = 0; t < T_; ++t) {
        if (tid < 64) xp[1 + tid] = x[(b * T_ + t) * 64 + tid];
        __syncthreads();

        // ---- layer 0 (FT=1) ----
        float a0 = 0.f, a1 = 0.f, a2 = 0.f, a3 = 0.f;
        rowacc1<64>(xp + fA, wl0 + chA * 4, a0, a1, a2, a3);
#pragma unroll
        for (int r = 0; r < 16; ++r)
            rowacc1<64>(h0p + r * ROWLEN + fA, wl0 + ((1 + r) * 3) * 64 + chA * 4, a0, a1, a2, a3);

        float cold0 = c0[chA * 64 + fA];
        float cc0 = fsig_(a1 + bs0[16 + chA]) * cold0 +
                    fsig_(a0 + bs0[chA]) * ftanh_(a3 + bs0[48 + chA]);
        float hh0 = fsig_(a2 + bs0[32 + chA]) * ftanh_(cc0);
        __syncthreads();
        h0p[chA * ROWLEN + 1 + fA] = hh0;
        c0[chA * 64 + fA] = cc0;
        __syncthreads();

        // ---- layer 1 (FT=2) ----
        float b00 = 0.f, b01 = 0.f, b10 = 0.f, b11 = 0.f;
        float b20 = 0.f, b21 = 0.f, b30 = 0.f, b31 = 0.f;
#pragma unroll
        for (int r = 0; r < 16; ++r)
            rowacc2<128>(h0p + r * ROWLEN + fB, wl1 + (r * 3) * 128 + chB * 4,
                         b00, b01, b10, b11, b20, b21, b30, b31);
#pragma unroll
        for (int r = 0; r < 32; ++r)
            rowacc2<128>(h1p + r * ROWLEN + fB, wl1 + ((16 + r) * 3) * 128 + chB * 4,
                         b00, b01, b10, b11, b20, b21, b30, b31);

        float bi = bs1[chB], bf = bs1[32 + chB], bo = bs1[64 + chB], bg = bs1[96 + chB];
        float co0 = c1[chB * 64 + fB], co1 = c1[chB * 64 + fB + 1];
        float cn0 = fsig_(b10 + bf) * co0 + fsig_(b00 + bi) * ftanh_(b30 + bg);
        float cn1 = fsig_(b11 + bf) * co1 + fsig_(b01 + bi) * ftanh_(b31 + bg);
        float hn0 = fsig_(b20 + bo) * ftanh_(cn0);
        float hn1 = fsig_(b21 + bo) * ftanh_(cn1);
        __syncthreads();
        h1p[chB * ROWLEN + 1 + fB] = hn0;
        h1p[chB * ROWLEN + 1 + fB + 1] = hn1;
        c1[chB * 64 + fB] = cn0;
        c1[chB * 64 + fB + 1] = cn1;
        *reinterpret_cast<float2*>(&seq[(((size_t)t * B_ + b) * 32 + chB) * 64 + fB]) =
            make_float2(hn0, hn1);
        __syncthreads();
    }

    for (int i = tid; i < 16 * 64; i += 1024) {
        int ch = i >> 6, f = i & 63;
        h1f[(b * 16 + ch) * 64 + f] = h0p[ch * ROWLEN + 1 + f];
        c1f[(b * 16 + ch) * 64 + f] = c0[i];
    }
    for (int i = tid; i < 32 * 64; i += 1024) {
        int ch = i >> 6, f = i & 63;
        h2f[(b * 32 + ch) * 64 + f] = h1p[ch * ROWLEN + 1 + f];
        c2f[(b * 32 + ch) * 64 + f] = c1[i];
    }
}

// ---------------------------------------------------------------------------
// Kernel 2: decoder layer 0 (32+32 -> 32), init (h2f,c2f); seq updated in place
// ---------------------------------------------------------------------------
__global__ __launch_bounds__(1024, 4) void dec0_kernel(
    const float* __restrict__ w, const float* __restrict__ bias,
    float* __restrict__ seq,
    const float* __restrict__ h2f, const float* __restrict__ c2f)
{
    __shared__ float wl[192 * 128];    // r<64, CH=32
    __shared__ float bs[128];
    __shared__ float xin[32 * ROWLEN];
    __shared__ float hp[32 * ROWLEN];
    __shared__ float c[32 * 64];

    const int tid = threadIdx.x;
    const int b = blockIdx.x;

    for (int idx = tid; idx < 192 * 128; idx += 1024) {
        int k = idx >> 7, r = idx & 127;
        int ch = r >> 2, g = r & 3;
        int ci = k / 3, d = k - ci * 3;
        wl[idx] = w[((g * 32 + ch) * 64 + ci) * 9 + d * 3 + 1];
    }
    if (tid < 128) bs[tid] = bias[tid];
    for (int i = tid; i < 32 * ROWLEN; i += 1024) { xin[i] = 0.f; hp[i] = 0.f; }
    __syncthreads();
    for (int i = tid; i < 32 * 64; i += 1024) {
        int ch = i >> 6, f = i & 63;
        hp[ch * ROWLEN + 1 + f] = h2f[(b * 32 + ch) * 64 + f];
        c[i] = c2f[(b * 32 + ch) * 64 + f];
    }
    __syncthreads();

    const int ch = tid >> 5, f0 = (tid & 31) * 2;

    for (int t = 0; t < T_; ++t) {
        {   // stage input tile: 1024 threads x float2 = 2048 floats, coalesced
            float2 vv = *reinterpret_cast<const float2*>(
                &seq[((size_t)t * B_ + b) * 2048 + tid * 2]);
            int ci = (tid * 2) >> 6, f = (tid * 2) & 63;
            *reinterpret_cast<float2*>(&xin[ci * ROWLEN + 1 + f]) = vv;
        }
        __syncthreads();

        float a00 = 0.f, a01 = 0.f, a10 = 0.f, a11 = 0.f;
        float a20 = 0.f, a21 = 0.f, a30 = 0.f, a31 = 0.f;
#pragma unroll
        for (int r = 0; r < 32; ++r)
            rowacc2<128>(xin + r * ROWLEN + f0, wl + (r * 3) * 128 + ch * 4,
                         a00, a01, a10, a11, a20, a21, a30, a31);
#pragma unroll
        for (int r = 0; r < 32; ++r)
            rowacc2<128>(hp + r * ROWLEN + f0, wl + ((32 + r) * 3) * 128 + ch * 4,
                         a00, a01, a10, a11, a20, a21, a30, a31);

        float bi = bs[ch], bf = bs[32 + ch], bo = bs[64 + ch], bg = bs[96 + ch];
        float co0 = c[ch * 64 + f0], co1 = c[ch * 64 + f0 + 1];
        float cn0 = fsig_(a10 + bf) * co0 + fsig_(a00 + bi) * ftanh_(a30 + bg);
        float cn1 = fsig_(a11 + bf) * co1 + fsig_(a01 + bi) * ftanh_(a31 + bg);
        float hn0 = fsig_(a20 + bo) * ftanh_(cn0);
        float hn1 = fsig_(a21 + bo) * ftanh_(cn1);
        __syncthreads();
        hp[ch * ROWLEN + 1 + f0] = hn0;
        hp[ch * ROWLEN + 1 + f0 + 1] = hn1;
        c[ch * 64 + f0] = cn0;
        c[ch * 64 + f0 + 1] = cn1;
        *reinterpret_cast<float2*>(&seq[((size_t)t * B_ + b) * 2048 + ch * 64 + f0]) =
            make_float2(hn0, hn1);   // in place
    }
}

// ---------------------------------------------------------------------------
// Kernel 3: decoder layer 1 (32+16 -> 16) + final 1x1 conv
// ---------------------------------------------------------------------------
__global__ __launch_bounds__(1024, 4) void dec1_kernel(
    const float* __restrict__ w, const float* __restrict__ bias,
    const float* __restrict__ seq,
    const float* __restrict__ h1f, const float* __restrict__ c1f,
    const float* __restrict__ fw, const float* __restrict__ fb,
    float* __restrict__ out)
{
    __shared__ float wl[144 * 64];     // r<48, CH=16
    __shared__ float bs[64];
    __shared__ float xin[32 * ROWLEN];
    __shared__ float hp[16 * ROWLEN];
    __shared__ float c[16 * 64];
    __shared__ float fcw[16];
    __shared__ float fcb;

    const int tid = threadIdx.x;
    const int b = blockIdx.x;

    for (int idx = tid; idx < 144 * 64; idx += 1024) {
        int k = idx >> 6, r = idx & 63;
        int ch = r >> 2, g = r & 3;
        int ci = k / 3, d = k - ci * 3;
        wl[idx] = w[((g * 16 + ch) * 48 + ci) * 9 + d * 3 + 1];
    }
    if (tid < 64) bs[tid] = bias[tid];
    if (tid < 16) fcw[tid] = fw[tid];
    if (tid == 16) fcb = fb[0];
    for (int i = tid; i < 32 * ROWLEN; i += 1024) xin[i] = 0.f;
    for (int i = tid; i < 16 * ROWLEN; i += 1024) hp[i] = 0.f;
    __syncthreads();
    for (int i = tid; i < 16 * 64; i += 1024) {
        int ch = i >> 6, f = i & 63;
        hp[ch * ROWLEN + 1 + f] = h1f[(b * 16 + ch) * 64 + f];
        c[i] = c1f[(b * 16 + ch) * 64 + f];
    }
    __syncthreads();

    const int ch = tid >> 6, f = tid & 63;   // 16ch x 64f, FT=1

    for (int t = 0; t < T_; ++t) {
        {
            float2 vv = *reinterpret_cast<const float2*>(
                &seq[((size_t)t * B_ + b) * 2048 + tid * 2]);
            int ci = (tid * 2) >> 6, ff = (tid * 2) & 63;
            *reinterpret_cast<float2*>(&xin[ci * ROWLEN + 1 + ff]) = vv;
        }
        __syncthreads();

        float a0 = 0.f, a1 = 0.f, a2 = 0.f, a3 = 0.f;
#pragma unroll
        for (int r = 0; r < 32; ++r)
            rowacc1<64>(xin + r * ROWLEN + f, wl + (r * 3) * 64 + ch * 4, a0, a1, a2, a3);
#pragma unroll
        for (int r = 0; r < 16; ++r)
            rowacc1<64>(hp + r * ROWLEN + f, wl + ((32 + r) * 3) * 64 + ch * 4, a0, a1, a2, a3);

        float cold = c[ch * 64 + f];
        float cc = fsig_(a1 + bs[16 + ch]) * cold +
                   fsig_(a0 + bs[ch]) * ftanh_(a3 + bs[48 + ch]);
        float hh = fsig_(a2 + bs[32 + ch]) * ftanh_(cc);
        __syncthreads();
        hp[ch * ROWLEN + 1 + f] = hh;
        c[ch * 64 + f] = cc;
        __syncthreads();

        if (tid < 64) {
            float a = fcb;
#pragma unroll
            for (int k2 = 0; k2 < 16; ++k2)
                a = fmaf(fcw[k2], hp[k2 * ROWLEN + 1 + tid], a);
            out[(b * T_ + t) * 64 + tid] = a;
        }
        __syncthreads();
    }
}

// ---------------------------------------------------------------------------
extern "C" void kernel_launch(void* const* d_in, const int* in_sizes, int n_in,
                              void* d_out, int out_size, void* d_ws, size_t ws_size,
                              hipStream_t stream)
{
    (void)in_sizes; (void)n_in; (void)out_size; (void)ws_size;
    const float* x   = (const float*)d_in[0];
    const float* ew0 = (const float*)d_in[1];
    const float* eb0 = (const float*)d_in[2];
    const float* ew1 = (const float*)d_in[3];
    const float* eb1 = (const float*)d_in[4];
    const float* dw0 = (const float*)d_in[5];
    const float* db0 = (const float*)d_in[6];
    const float* dw1 = (const float*)d_in[7];
    const float* db1 = (const float*)d_in[8];
    const float* fw  = (const float*)d_in[9];
    const float* fb  = (const float*)d_in[10];
    float* out = (float*)d_out;

    float* ws  = (float*)d_ws;
    float* seq = ws;                                     // [T][B][32][64]
    float* h1f = seq + (size_t)T_ * B_ * 32 * 64;        // [B][16][64]
    float* c1f = h1f + (size_t)B_ * 16 * 64;
    float* h2f = c1f + (size_t)B_ * 16 * 64;             // [B][32][64]
    float* c2f = h2f + (size_t)B_ * 32 * 64;

    enc_kernel<<<B_, 1024, 0, stream>>>(x, ew0, eb0, ew1, eb1, seq, h1f, c1f, h2f, c2f);
    dec0_kernel<<<B_, 1024, 0, stream>>>(dw0, db0, seq, h2f, c2f);
    dec1_kernel<<<B_, 1024, 0, stream>>>(dw1, db1, seq, h1f, c1f, fw, fb, out);
}